// Round 1
// baseline (10451.832 us; speedup 1.0000x reference)
//
#include <hip/hip_runtime.h>
#include <hip/hip_bf16.h>

// ============================================================================
// UpConvsample2d: transposed-conv 2x upsample (512->256 ch, 3x3) + FIR
// [1,3,1]x[1,3,1]*4/25 smoothing, crop to 128x128, fp32 out.
//
// Math (derived from reference):
//   W1 = w viewed flat as (512,256,3,3):  W1[c,o,a,b] = w[((c*256+o)*3+a)*3+b]
//   y1[n,o,h',w'] = sum_c sum_{rowtaps x coltaps} x[n,c,r,s] * W1[c,o,a,b]
//     h'=2i   : (r=i-1,a=2),(r=i,a=0)      h'=2i+1 : (r=i,a=1)
//     w'=2j   : (s=j-1,b=2),(s=j,b=0)      w'=2j+1 : (s=j,b=1)
//     (r,s clamped: contributions with r<0 or s<0 are zero)
//   out[n,o,h,w] = sum_{u,v in [0,3)} fr[u]*fr[v]*y1[h-2+u, w-2+v],
//     fr = {0.4,1.2,0.4}, zero for negative idx; indices never reach 128.
// => y1 needed only on [0,128)^2 -> 4 parity planes of exactly 64x64.
//
// ws layout: yp[p][n][o][i][j] bf16, p = (h'&1)*2 + (w'&1), dims 4x16x256x64x64
// ============================================================================

#define Y_ELEMS (4u * 16u * 256u * 64u * 64u)   // 67,108,864

// ---------------------------------------------------------------- phase 1 ---
template <int PH, int PW>
__global__ __launch_bounds__(256) void conv_up_kernel(
    const float* __restrict__ x, const float* __restrict__ w,
    __hip_bfloat16* __restrict__ yp)
{
    constexpr int NRT = PH ? 1 : 2;
    constexpr int NCT = PW ? 1 : 2;
    constexpr int NTAP = NRT * NCT;
    constexpr int P = PH * 2 + PW;

    const int ob = blockIdx.x;      // o block (0..3), 64 channels each
    const int i  = blockIdx.y;      // 0..63
    const int n  = blockIdx.z;      // 0..15

    const int tx = threadIdx.x & 63;   // j
    const int ty = threadIdx.x >> 6;   // 0..3 (o subgroup)
    const int j  = tx;
    const int o0 = ob * 64;

    // tap tables
    int rr[NRT];
    if (PH) { rr[0] = i; } else { rr[0] = i - 1; rr[1] = i; }
    int ss[NCT];
    if (PW) { ss[0] = j; } else { ss[0] = j - 1; ss[1] = j; }

    __shared__ float wlds[16][NTAP][64];   // [cc][tap][o_local]

    float acc[16];
#pragma unroll
    for (int r = 0; r < 16; r++) acc[r] = 0.f;

    for (int c0 = 0; c0 < 512; c0 += 16) {
        __syncthreads();
        // stage W tile: W1[c0+cc, o0+ol, a(t), b(t)]
        constexpr int NE = 16 * NTAP * 64;
        for (int e = (int)threadIdx.x; e < NE; e += 256) {
            int ol = e & 63;
            int t  = (e >> 6) % NTAP;
            int cc = (e >> 6) / NTAP;
            int rt = t / NCT, ct = t % NCT;
            int a = PH ? 1 : (rt == 0 ? 2 : 0);
            int b = PW ? 1 : (ct == 0 ? 2 : 0);
            int c = c0 + cc;
            wlds[cc][t][ol] = w[((size_t)(c * 256 + (o0 + ol)) * 3 + a) * 3 + b];
        }
        __syncthreads();

        for (int cc = 0; cc < 16; cc++) {
            int c = c0 + cc;
            const float* xb = x + ((size_t)(n * 512 + c) << 12);
            float xv[NTAP];
#pragma unroll
            for (int rt = 0; rt < NRT; rt++) {
#pragma unroll
                for (int ct = 0; ct < NCT; ct++) {
                    int r = rr[rt], s = ss[ct];
                    float v = 0.f;
                    if (r >= 0 && s >= 0) v = xb[(r << 6) + s];
                    xv[rt * NCT + ct] = v;
                }
            }
#pragma unroll
            for (int t = 0; t < NTAP; t++) {
                float xvv = xv[t];
#pragma unroll
                for (int r16 = 0; r16 < 16; r16++)
                    acc[r16] = fmaf(xvv, wlds[cc][t][ty * 16 + r16], acc[r16]);
            }
        }
    }

#pragma unroll
    for (int r16 = 0; r16 < 16; r16++) {
        int o = o0 + ty * 16 + r16;
        size_t oi = ((size_t)((P * 16 + n) * 256 + o) << 12) + (i << 6) + j;
        yp[oi] = __float2bfloat16(acc[r16]);
    }
}

// ---------------------------------------------------------------- phase 2 ---
__global__ __launch_bounds__(256) void fir_kernel(
    const __hip_bfloat16* __restrict__ yp, float* __restrict__ out)
{
    int idx = blockIdx.x * 256 + (int)threadIdx.x;  // 67.1M
    int w_  = idx & 127;
    int h   = (idx >> 7) & 127;
    int no  = idx >> 14;            // n*256 + o
    const float fr[3] = {0.4f, 1.2f, 0.4f};

    float acc = 0.f;
#pragma unroll
    for (int u = 0; u < 3; u++) {
        int hh = h - 2 + u;
        if (hh < 0) continue;
        int ih = hh >> 1, ph = hh & 1;
#pragma unroll
        for (int v = 0; v < 3; v++) {
            int ww = w_ - 2 + v;
            if (ww < 0) continue;
            int jw = ww >> 1, pw = ww & 1;
            int p = ph * 2 + pw;
            float yv = __bfloat162float(
                yp[((size_t)(p * 4096 + no) << 12) + (ih << 6) + jw]);
            acc += fr[u] * fr[v] * yv;
        }
    }
    out[idx] = acc;
}

// ------------------------------------------------- fallback (ws too small) --
// Fused composite-weight direct conv: out = FIR o UpConv folded into per-pixel
// composite coefficients. Slow but correct; only used if ws_size < 134 MB.
__global__ __launch_bounds__(256) void fused_direct_kernel(
    const float* __restrict__ x, const float* __restrict__ w,
    float* __restrict__ out)
{
    int idx = blockIdx.x * 256 + (int)threadIdx.x;
    int w_  = idx & 127;
    int h   = (idx >> 7) & 127;
    int no  = idx >> 14;
    int o = no & 255;
    int n = no >> 8;
    int I = h >> 1, J = w_ >> 1;
    const float fr0 = 0.4f, fr1 = 1.2f, fr2 = 0.4f;

    // composite row coefficients: out row h draws x rows rh[dr] with weight
    // vector gh[dr][a] multiplying W1[.,.,a,.]
    float gh[3][3]; int rh[3]; int nh;
    if ((h & 1) == 0) {
        nh = 3;
        rh[0] = I - 2; gh[0][0] = 0.f; gh[0][1] = 0.f; gh[0][2] = fr0;
        rh[1] = I - 1; gh[1][0] = fr0; gh[1][1] = fr1; gh[1][2] = fr2;
        rh[2] = I;     gh[2][0] = fr2; gh[2][1] = 0.f; gh[2][2] = 0.f;
    } else {
        nh = 2;
        rh[0] = I - 1; gh[0][0] = 0.f; gh[0][1] = fr0; gh[0][2] = fr1;
        rh[1] = I;     gh[1][0] = fr1; gh[1][1] = fr2; gh[1][2] = 0.f;
    }
    float gw[3][3]; int cw[3]; int nw;
    if ((w_ & 1) == 0) {
        nw = 3;
        cw[0] = J - 2; gw[0][0] = 0.f; gw[0][1] = 0.f; gw[0][2] = fr0;
        cw[1] = J - 1; gw[1][0] = fr0; gw[1][1] = fr1; gw[1][2] = fr2;
        cw[2] = J;     gw[2][0] = fr2; gw[2][1] = 0.f; gw[2][2] = 0.f;
    } else {
        nw = 2;
        cw[0] = J - 1; gw[0][0] = 0.f; gw[0][1] = fr0; gw[0][2] = fr1;
        cw[1] = J;     gw[1][0] = fr1; gw[1][1] = fr2; gw[1][2] = 0.f;
    }

    float acc = 0.f;
    for (int c = 0; c < 512; c++) {
        const float* xb = x + ((size_t)(n * 512 + c) << 12);
        const float* wb = w + (size_t)(c * 256 + o) * 9;
        float tmp[3][3];   // [dr][b]
#pragma unroll
        for (int dr = 0; dr < 3; dr++)
            tmp[dr][0] = tmp[dr][1] = tmp[dr][2] = 0.f;
        for (int dr = 0; dr < nh; dr++) {
            int r = rh[dr]; if (r < 0) continue;
            for (int ds = 0; ds < nw; ds++) {
                int s = cw[ds]; if (s < 0) continue;
                float xv = xb[(r << 6) + s];
                tmp[dr][0] += gw[ds][0] * xv;
                tmp[dr][1] += gw[ds][1] * xv;
                tmp[dr][2] += gw[ds][2] * xv;
            }
        }
#pragma unroll
        for (int a = 0; a < 3; a++) {
            float xg0 = 0.f, xg1 = 0.f, xg2 = 0.f;
            for (int dr = 0; dr < nh; dr++) {
                float g = gh[dr][a];
                xg0 += g * tmp[dr][0];
                xg1 += g * tmp[dr][1];
                xg2 += g * tmp[dr][2];
            }
            acc += xg0 * wb[a * 3 + 0] + xg1 * wb[a * 3 + 1] + xg2 * wb[a * 3 + 2];
        }
    }
    out[idx] = acc;
}

// ---------------------------------------------------------------- launch ----
extern "C" void kernel_launch(void* const* d_in, const int* in_sizes, int n_in,
                              void* d_out, int out_size, void* d_ws, size_t ws_size,
                              hipStream_t stream)
{
    (void)in_sizes; (void)n_in; (void)out_size;
    const float* x = (const float*)d_in[0];   // (16,512,64,64)
    const float* w = (const float*)d_in[1];   // (256,512,3,3) -> W1 (512,256,3,3)
    float* out = (float*)d_out;               // (16,256,128,128)

    const size_t need = (size_t)Y_ELEMS * sizeof(__hip_bfloat16);  // 134 MB
    if (ws_size >= need) {
        __hip_bfloat16* yp = (__hip_bfloat16*)d_ws;
        dim3 g(4, 64, 16), b(256);
        conv_up_kernel<0, 0><<<g, b, 0, stream>>>(x, w, yp);
        conv_up_kernel<0, 1><<<g, b, 0, stream>>>(x, w, yp);
        conv_up_kernel<1, 0><<<g, b, 0, stream>>>(x, w, yp);
        conv_up_kernel<1, 1><<<g, b, 0, stream>>>(x, w, yp);
        fir_kernel<<<dim3(Y_ELEMS / 256), dim3(256), 0, stream>>>(yp, out);
    } else {
        fused_direct_kernel<<<dim3(Y_ELEMS / 256), dim3(256), 0, stream>>>(x, w, out);
    }
}

// Round 2
// 744.674 us; speedup vs baseline: 14.0354x; 14.0354x over previous
//
#include <hip/hip_runtime.h>
#include <hip/hip_bf16.h>

// ============================================================================
// UpConvsample2d via bf16 MFMA.
//
// Math (verified in round 1):
//   W1[c,o,a,b] = w[((c*256+o)*3+a)*3+b]
//   y1 parity planes p=(h'&1)*2+(w'&1), each 64x64 per (n,o):
//     ph=0 row taps: (r=i-1,a=2),(r=i,a=0)   ph=1: (r=i,a=1)   (cols same)
//   out = 3x3 FIR {0.4,1.2,0.4}^2 over y1 with top/left pad 2, crop 128x128.
//
// Phases:
//   1. pack x -> xp[n][65][65][512] bf16 (padded channel-last), w -> wp[ab][o][c]
//   2. mfma_conv: per parity, sum over taps of GEMM (M=spatial, N=o, K=c)
//      128x128 tile, 4 waves x (64x64), 16x16x32 bf16 MFMA, global_load_lds(16B)
//   3. fir_quad: 2x2 output quad per thread from 16 y taps
// ============================================================================

typedef __attribute__((ext_vector_type(8))) short short8;
typedef __attribute__((ext_vector_type(4))) float float4v;

#define XP_ELEMS ((size_t)16 * 65 * 65 * 512)   // 34,611,200
#define WP_ELEMS ((size_t)9 * 256 * 512)        // 1,179,648
#define YP_ELEMS ((size_t)4 * 16 * 256 * 4096)  // 67,108,864

__device__ __forceinline__ void gl_lds16(const __hip_bfloat16* g, __hip_bfloat16* l) {
    __builtin_amdgcn_global_load_lds(
        (const __attribute__((address_space(1))) void*)g,
        (__attribute__((address_space(3))) void*)l, 16, 0, 0);
}

// --------------------------------------------------------------- pack / pad -
__global__ __launch_bounds__(256) void zero_pad_kernel(__hip_bfloat16* __restrict__ xp) {
    int idx = blockIdx.x * 256 + (int)threadIdx.x;  // 16*65*512
    if (idx >= 16 * 65 * 512) return;
    int c = idx & 511;
    int t = (idx >> 9) % 65;
    int n = idx / (65 * 512);
    __hip_bfloat16 z = __float2bfloat16(0.f);
    xp[(((size_t)(n * 65) + 0) * 65 + t) * 512 + c] = z;   // pad row 0
    xp[(((size_t)(n * 65) + t) * 65 + 0) * 512 + c] = z;   // pad col 0
}

__global__ __launch_bounds__(256) void pack_w_kernel(
    const float* __restrict__ w, __hip_bfloat16* __restrict__ wp) {
    int idx = blockIdx.x * 256 + (int)threadIdx.x;  // 9*256*512
    int c  = idx & 511;
    int o  = (idx >> 9) & 255;
    int ab = idx >> 17;                  // 0..8
    int a = ab / 3, b = ab % 3;
    wp[idx] = __float2bfloat16(w[((size_t)(c * 256 + o) * 3 + a) * 3 + b]);
}

__global__ __launch_bounds__(256) void pack_x_kernel(
    const float* __restrict__ x, __hip_bfloat16* __restrict__ xp) {
    int i = blockIdx.x;       // 0..63
    int n = blockIdx.y;       // 0..15
    int tid = (int)threadIdx.x;
    __shared__ float tile[64][65];
    for (int c0 = 0; c0 < 512; c0 += 64) {
        __syncthreads();
#pragma unroll
        for (int rr = 0; rr < 16; rr++) {
            int cl = (tid >> 6) * 16 + rr;
            int j = tid & 63;
            tile[cl][j] = x[(((size_t)(n * 512 + c0 + cl) * 64) + i) * 64 + j];
        }
        __syncthreads();
#pragma unroll
        for (int jj = 0; jj < 16; jj++) {
            int j = (tid >> 6) * 16 + jj;
            int cl = tid & 63;
            xp[(((size_t)(n * 65) + i + 1) * 65 + (j + 1)) * 512 + c0 + cl] =
                __float2bfloat16(tile[cl][j]);
        }
    }
}

// ---------------------------------------------------------------- mfma conv -
// grid: (2 N-tiles, 512 M-tiles, 4 parities), block 256 (4 waves)
__global__ __launch_bounds__(256) void mfma_conv_kernel(
    const __hip_bfloat16* __restrict__ xp, const __hip_bfloat16* __restrict__ wp,
    __hip_bfloat16* __restrict__ yp) {
    const int p  = blockIdx.z, ph = p >> 1, pw = p & 1;
    const int o0 = blockIdx.x * 128;
    const int mt = blockIdx.y;
    const int n  = mt >> 5;
    const int i0 = (mt & 31) << 1;      // block covers rows i0, i0+1
    const int tid  = (int)threadIdx.x;
    const int wave = tid >> 6, lane = tid & 63;
    const int wm = wave & 1, wn = wave >> 1;
    const int lrow = lane & 15, quad = lane >> 4;
    const int m0j   = wave * 16 + (lane >> 2);   // A/B tile row this lane stages
    const int klane = (lane & 3) * 8;            // k element offset this lane stages

    __shared__ __align__(16) __hip_bfloat16 lA[128 * 32];
    __shared__ __align__(16) __hip_bfloat16 lB[128 * 32];

    float4v acc[4][4];
#pragma unroll
    for (int fm = 0; fm < 4; fm++)
#pragma unroll
        for (int fn = 0; fn < 4; fn++) acc[fm][fn] = (float4v)0.f;

    __hip_bfloat16* la0 = lA + wave * 512;          // e=0 rows (di=0)
    __hip_bfloat16* la1 = lA + 2048 + wave * 512;   // e=1 rows (di=1)
    __hip_bfloat16* lb0 = lB + wave * 512;
    __hip_bfloat16* lb1 = lB + 2048 + wave * 512;

    const int nrt = ph ? 1 : 2, nct = pw ? 1 : 2;
    for (int rt = 0; rt < nrt; rt++) {
        const int drp = ph ? 1 : rt;            // padded row offset: r+1 = i + drp
        const int a   = ph ? 1 : (rt ? 0 : 2);
        for (int ct = 0; ct < nct; ct++) {
            const int dsp = pw ? 1 : ct;
            const int b   = pw ? 1 : (ct ? 0 : 2);
            const int ab  = a * 3 + b;
            const __hip_bfloat16* A0 =
                xp + (((size_t)(n * 65 + i0 + drp)) * 65 + m0j + dsp) * 512 + klane;
            const __hip_bfloat16* A1 = A0 + (size_t)65 * 512;
            const __hip_bfloat16* B0 =
                wp + ((size_t)(ab * 256 + o0 + m0j)) * 512 + klane;
            const __hip_bfloat16* B1 = B0 + (size_t)64 * 512;

            for (int c0 = 0; c0 < 512; c0 += 32) {
                __syncthreads();
                gl_lds16(A0 + c0, la0);
                gl_lds16(A1 + c0, la1);
                gl_lds16(B0 + c0, lb0);
                gl_lds16(B1 + c0, lb1);
                __syncthreads();
                short8 af[4], bv[4];
#pragma unroll
                for (int fm = 0; fm < 4; fm++)
                    af[fm] = *(const short8*)(lA + ((wm * 64 + fm * 16 + lrow) * 32 + quad * 8));
#pragma unroll
                for (int fn = 0; fn < 4; fn++)
                    bv[fn] = *(const short8*)(lB + ((wn * 64 + fn * 16 + lrow) * 32 + quad * 8));
#pragma unroll
                for (int fm = 0; fm < 4; fm++)
#pragma unroll
                    for (int fn = 0; fn < 4; fn++)
                        acc[fm][fn] = __builtin_amdgcn_mfma_f32_16x16x32_bf16(
                            af[fm], bv[fn], acc[fm][fn], 0, 0, 0);
            }
        }
    }

    // epilogue: D row=(quad*4+reg) -> j, col=lrow -> o ; 4 consecutive j per lane
#pragma unroll
    for (int fm = 0; fm < 4; fm++) {
        int j0 = fm * 16 + quad * 4;
#pragma unroll
        for (int fn = 0; fn < 4; fn++) {
            int o = o0 + wn * 64 + fn * 16 + lrow;
            union { ushort4 v; __hip_bfloat16 h[4]; } u;
#pragma unroll
            for (int r = 0; r < 4; r++) u.h[r] = __float2bfloat16(acc[fm][fn][r]);
            *(ushort4*)(yp + (((size_t)(p * 4096 + n * 256 + o)) << 12) +
                        ((i0 + wm) << 6) + j0) = u.v;
        }
    }
}

// ---------------------------------------------------------------- FIR quad --
// thread -> (n,o,I,J): outputs (2I,2J),(2I,2J+1),(2I+1,2J),(2I+1,2J+1)
__global__ __launch_bounds__(256) void fir_quad_kernel(
    const __hip_bfloat16* __restrict__ yp, float* __restrict__ out) {
    int idx = blockIdx.x * 256 + (int)threadIdx.x;  // 16*256*64*64
    int J = idx & 63, I = (idx >> 6) & 63, no = idx >> 12;

    float Y[2][2][2][2];  // [ph][pw][k(row I-1+k)][l(col J-1+l)]
#pragma unroll
    for (int phh = 0; phh < 2; phh++)
#pragma unroll
        for (int pww = 0; pww < 2; pww++)
#pragma unroll
            for (int k = 0; k < 2; k++)
#pragma unroll
                for (int l = 0; l < 2; l++) {
                    int ih = I - 1 + k, jw = J - 1 + l;
                    float v = 0.f;
                    if (ih >= 0 && jw >= 0)
                        v = __bfloat162float(
                            yp[(((size_t)((phh * 2 + pww) * 4096 + no)) << 12) +
                               (ih << 6) + jw]);
                    Y[phh][pww][k][l] = v;
                }

    // weight of plane-parity q, offset k, for output sub-parity e
    const float rw[2][2][2] = {{{0.4f, 0.4f}, {1.2f, 0.f}},
                               {{0.f, 1.2f}, {0.4f, 0.4f}}};  // [e][q][k]

    float cs[2][2][2];  // [ph][k][ew]
#pragma unroll
    for (int phh = 0; phh < 2; phh++)
#pragma unroll
        for (int k = 0; k < 2; k++)
#pragma unroll
            for (int ew = 0; ew < 2; ew++) {
                float s = 0.f;
#pragma unroll
                for (int pww = 0; pww < 2; pww++)
#pragma unroll
                    for (int l = 0; l < 2; l++)
                        s += rw[ew][pww][l] * Y[phh][pww][k][l];
                cs[phh][k][ew] = s;
            }

    float o_[2][2];
#pragma unroll
    for (int eh = 0; eh < 2; eh++)
#pragma unroll
        for (int ew = 0; ew < 2; ew++) {
            float s = 0.f;
#pragma unroll
            for (int phh = 0; phh < 2; phh++)
#pragma unroll
                for (int k = 0; k < 2; k++)
                    s += rw[eh][phh][k] * cs[phh][k][ew];
            o_[eh][ew] = s;
        }

    size_t base = ((size_t)no << 14) + ((size_t)(2 * I) << 7) + 2 * J;
    *(float2*)(out + base)       = make_float2(o_[0][0], o_[0][1]);
    *(float2*)(out + base + 128) = make_float2(o_[1][0], o_[1][1]);
}

// ------------------------------------------------- fallback (ws too small) --
__global__ __launch_bounds__(256) void fused_direct_kernel(
    const float* __restrict__ x, const float* __restrict__ w,
    float* __restrict__ out) {
    int idx = blockIdx.x * 256 + (int)threadIdx.x;
    int w_ = idx & 127, h = (idx >> 7) & 127, no = idx >> 14;
    int o = no & 255, n = no >> 8;
    int I = h >> 1, J = w_ >> 1;
    const float fr0 = 0.4f, fr1 = 1.2f, fr2 = 0.4f;
    float gh[3][3]; int rh[3]; int nh;
    if ((h & 1) == 0) {
        nh = 3;
        rh[0] = I - 2; gh[0][0] = 0.f; gh[0][1] = 0.f; gh[0][2] = fr0;
        rh[1] = I - 1; gh[1][0] = fr0; gh[1][1] = fr1; gh[1][2] = fr2;
        rh[2] = I;     gh[2][0] = fr2; gh[2][1] = 0.f; gh[2][2] = 0.f;
    } else {
        nh = 2;
        rh[0] = I - 1; gh[0][0] = 0.f; gh[0][1] = fr0; gh[0][2] = fr1;
        rh[1] = I;     gh[1][0] = fr1; gh[1][1] = fr2; gh[1][2] = 0.f;
    }
    float gw[3][3]; int cw[3]; int nw;
    if ((w_ & 1) == 0) {
        nw = 3;
        cw[0] = J - 2; gw[0][0] = 0.f; gw[0][1] = 0.f; gw[0][2] = fr0;
        cw[1] = J - 1; gw[1][0] = fr0; gw[1][1] = fr1; gw[1][2] = fr2;
        cw[2] = J;     gw[2][0] = fr2; gw[2][1] = 0.f; gw[2][2] = 0.f;
    } else {
        nw = 2;
        cw[0] = J - 1; gw[0][0] = 0.f; gw[0][1] = fr0; gw[0][2] = fr1;
        cw[1] = J;     gw[1][0] = fr1; gw[1][1] = fr2; gw[1][2] = 0.f;
    }
    float acc = 0.f;
    for (int c = 0; c < 512; c++) {
        const float* xb = x + ((size_t)(n * 512 + c) << 12);
        const float* wb = w + (size_t)(c * 256 + o) * 9;
        float tmp[3][3];
#pragma unroll
        for (int dr = 0; dr < 3; dr++) tmp[dr][0] = tmp[dr][1] = tmp[dr][2] = 0.f;
        for (int dr = 0; dr < nh; dr++) {
            int r = rh[dr]; if (r < 0) continue;
            for (int ds = 0; ds < nw; ds++) {
                int s = cw[ds]; if (s < 0) continue;
                float xv = xb[(r << 6) + s];
                tmp[dr][0] += gw[ds][0] * xv;
                tmp[dr][1] += gw[ds][1] * xv;
                tmp[dr][2] += gw[ds][2] * xv;
            }
        }
#pragma unroll
        for (int a = 0; a < 3; a++) {
            float xg0 = 0.f, xg1 = 0.f, xg2 = 0.f;
            for (int dr = 0; dr < nh; dr++) {
                float g = gh[dr][a];
                xg0 += g * tmp[dr][0]; xg1 += g * tmp[dr][1]; xg2 += g * tmp[dr][2];
            }
            acc += xg0 * wb[a * 3] + xg1 * wb[a * 3 + 1] + xg2 * wb[a * 3 + 2];
        }
    }
    out[idx] = acc;
}

// ---------------------------------------------------------------- launch ----
extern "C" void kernel_launch(void* const* d_in, const int* in_sizes, int n_in,
                              void* d_out, int out_size, void* d_ws, size_t ws_size,
                              hipStream_t stream)
{
    (void)in_sizes; (void)n_in; (void)out_size;
    const float* x = (const float*)d_in[0];   // (16,512,64,64)
    const float* w = (const float*)d_in[1];   // (256,512,3,3)
    float* out = (float*)d_out;               // (16,256,128,128)

    const size_t need = (XP_ELEMS + WP_ELEMS + YP_ELEMS) * sizeof(__hip_bfloat16);
    if (ws_size >= need) {
        __hip_bfloat16* xp = (__hip_bfloat16*)d_ws;
        __hip_bfloat16* wp = xp + XP_ELEMS;
        __hip_bfloat16* yp = wp + WP_ELEMS;
        zero_pad_kernel<<<dim3((16 * 65 * 512 + 255) / 256), dim3(256), 0, stream>>>(xp);
        pack_w_kernel<<<dim3((int)(WP_ELEMS / 256)), dim3(256), 0, stream>>>(w, wp);
        pack_x_kernel<<<dim3(64, 16), dim3(256), 0, stream>>>(x, xp);
        mfma_conv_kernel<<<dim3(2, 512, 4), dim3(256), 0, stream>>>(xp, wp, yp);
        fir_quad_kernel<<<dim3((int)(YP_ELEMS / 4 / 256)), dim3(256), 0, stream>>>(yp, out);
    } else {
        fused_direct_kernel<<<dim3((int)(YP_ELEMS / 256)), dim3(256), 0, stream>>>(x, w, out);
    }
}